// Round 7
// baseline (103.169 us; speedup 1.0000x reference)
//
#include <hip/hip_runtime.h>

#define T_LEN 2048

typedef float f4 __attribute__((ext_vector_type(4)));

// --- one timestep + one xi-conversion filler --------------------------------
// h_new[j] = relu( xi_t[j] + sum_k W_hh[j,k]*h[k] ),  xi precomputed = x*wih+b.
// 21 insts: filler-fma (independent -> absorbs the head interlock on h),
// fma(h,w0,xi), 15 fused DPP rotations (4 independent acc chains), add tree,
// max. First DPP read of h is 2 insts after the previous step's max write
// (R2/R6-proven hazard spacing). xo (= next chunk's xi element) is
// early-clobber so it can't alias any not-yet-read input.
__device__ __forceinline__ void step(float& h, float xi, float raw, float& xo,
                                     const float (&w)[16], float wih, float bias) {
  float a0, a1, a2, a3;
  asm("v_fma_f32 %[xo], %[raw], %[wih], %[bs]\n\t"
      "v_fma_f32 %[a0], %[h], %[w0], %[xi]\n\t"
      "v_mul_f32_dpp  %[a1], %[h], %[w1]  row_ror:1  row_mask:0xf bank_mask:0xf\n\t"
      "v_mul_f32_dpp  %[a2], %[h], %[w2]  row_ror:2  row_mask:0xf bank_mask:0xf\n\t"
      "v_mul_f32_dpp  %[a3], %[h], %[w3]  row_ror:3  row_mask:0xf bank_mask:0xf\n\t"
      "v_fmac_f32_dpp %[a0], %[h], %[w4]  row_ror:4  row_mask:0xf bank_mask:0xf\n\t"
      "v_fmac_f32_dpp %[a1], %[h], %[w5]  row_ror:5  row_mask:0xf bank_mask:0xf\n\t"
      "v_fmac_f32_dpp %[a2], %[h], %[w6]  row_ror:6  row_mask:0xf bank_mask:0xf\n\t"
      "v_fmac_f32_dpp %[a3], %[h], %[w7]  row_ror:7  row_mask:0xf bank_mask:0xf\n\t"
      "v_fmac_f32_dpp %[a0], %[h], %[w8]  row_ror:8  row_mask:0xf bank_mask:0xf\n\t"
      "v_fmac_f32_dpp %[a1], %[h], %[w9]  row_ror:9  row_mask:0xf bank_mask:0xf\n\t"
      "v_fmac_f32_dpp %[a2], %[h], %[w10] row_ror:10 row_mask:0xf bank_mask:0xf\n\t"
      "v_fmac_f32_dpp %[a3], %[h], %[w11] row_ror:11 row_mask:0xf bank_mask:0xf\n\t"
      "v_fmac_f32_dpp %[a0], %[h], %[w12] row_ror:12 row_mask:0xf bank_mask:0xf\n\t"
      "v_fmac_f32_dpp %[a1], %[h], %[w13] row_ror:13 row_mask:0xf bank_mask:0xf\n\t"
      "v_fmac_f32_dpp %[a2], %[h], %[w14] row_ror:14 row_mask:0xf bank_mask:0xf\n\t"
      "v_fmac_f32_dpp %[a3], %[h], %[w15] row_ror:15 row_mask:0xf bank_mask:0xf\n\t"
      "v_add_f32 %[a0], %[a0], %[a1]\n\t"
      "v_add_f32 %[a2], %[a2], %[a3]\n\t"
      "v_add_f32 %[a0], %[a0], %[a2]\n\t"
      "v_max_f32 %[h], 0, %[a0]"
      : [a0] "=&v"(a0), [a1] "=&v"(a1), [a2] "=&v"(a2), [a3] "=&v"(a3),
        [xo] "=&v"(xo), [h] "+v"(h)
      : [xi] "v"(xi), [raw] "v"(raw), [wih] "v"(wih), [bs] "v"(bias),
        [w0] "v"(w[0]),  [w1] "v"(w[1]),  [w2] "v"(w[2]),  [w3] "v"(w[3]),
        [w4] "v"(w[4]),  [w5] "v"(w[5]),  [w6] "v"(w[6]),  [w7] "v"(w[7]),
        [w8] "v"(w[8]),  [w9] "v"(w[9]),  [w10] "v"(w[10]), [w11] "v"(w[11]),
        [w12] "v"(w[12]), [w13] "v"(w[13]), [w14] "v"(w[14]), [w15] "v"(w[15]));
}

// Quad of steps: consume XI[4q..4q+3], convert RAW quad q -> XO[4q..4q+3].
#define Q4(XI, RQ, XO, q)                          \
  step(h, XI[4*(q)+0], RQ[q].x, XO[4*(q)+0], w, wih, bias); \
  step(h, XI[4*(q)+1], RQ[q].y, XO[4*(q)+1], w, wih, bias); \
  step(h, XI[4*(q)+2], RQ[q].z, XO[4*(q)+2], w, wih, bias); \
  step(h, XI[4*(q)+3], RQ[q].w, XO[4*(q)+3], w, wih, bias);

// 32 steps: consume xi-set XI, convert raw-set RQ into xi-set XO.
#define HALF(XI, RQ, XO) \
  Q4(XI, RQ, XO, 0) Q4(XI, RQ, XO, 1) Q4(XI, RQ, XO, 2) Q4(XI, RQ, XO, 3) \
  Q4(XI, RQ, XO, 4) Q4(XI, RQ, XO, 5) Q4(XI, RQ, XO, 6) Q4(XI, RQ, XO, 7)

#define LD8(R, PS) \
  R[0] = (PS)[0]; R[1] = (PS)[1]; R[2] = (PS)[2]; R[3] = (PS)[3]; \
  R[4] = (PS)[4]; R[5] = (PS)[5]; R[6] = (PS)[6]; R[7] = (PS)[7];

// --- kernel -----------------------------------------------------------------
__global__ __launch_bounds__(256, 1) void rnn_relu_kernel(
    const float* __restrict__ x, const float* __restrict__ W_ih,
    const float* __restrict__ b_ih, const float* __restrict__ W_hh,
    const float* __restrict__ b_hh, const float* __restrict__ W_fc,
    const float* __restrict__ b_fc, float* __restrict__ out) {
  const int tid = threadIdx.x;
  const int j   = tid & 15;                        // h index owned by this lane
  const int b   = blockIdx.x * 16 + (tid >> 4);    // batch per 16-lane row

  // Probe row_ror:1 direction (ctrl 0x121 == asm row_ror:1), R1/R2-proven.
  int pr = __builtin_amdgcn_update_dpp(0, j, 0x121, 0xF, 0xF, true);
  const bool plus = (pr == ((j + 1) & 15));

  // w[s] = W_hh[j][sigma_s(j)] so ror_s(h)*w[s] contributes W_hh[j,k]*h[k].
  float w[16];
#pragma unroll
  for (int s = 0; s < 16; ++s) {
    int k = (j + (plus ? s : (16 - s))) & 15;
    w[s] = W_hh[j * 16 + k];
  }
  const float wih  = W_ih[j];
  const float bias = b_ih[j] + b_hh[j];

  // x pipeline: chunk = 32 steps = 8 f4. Raw loaded 2 chunks ahead of
  // consumption (issued only when the target set's last read is done),
  // converted raw->xi 1 chunk ahead via the per-step filler fma.
  const f4* __restrict__ xr = (const f4*)(x + (size_t)b * T_LEN);

  f4 RA[8], RB[8];
  float XA[32], XB[32];
  LD8(RA, xr)          // chunk 0
  LD8(RB, xr + 8)      // chunk 1
#pragma unroll
  for (int i = 0; i < 8; ++i) {    // preamble: chunk0 raw -> XA
    XA[4*i+0] = fmaf(RA[i].x, wih, bias);
    XA[4*i+1] = fmaf(RA[i].y, wih, bias);
    XA[4*i+2] = fmaf(RA[i].z, wih, bias);
    XA[4*i+3] = fmaf(RA[i].w, wih, bias);
  }

  float h = 0.0f;
  const f4* p2 = xr + 16;          // chunk 2 source

#pragma unroll 1
  for (int k = 0; k < 64; k += 2) {
    // even half: consume XA (chunk k), convert RB->XB (chunk k+1),
    //            load RA <- chunk k+2 (RA's last read was previous odd half)
    const f4* psA = (k + 2 < 64) ? p2 : xr;        // wrap: dummy reload
    LD8(RA, psA)
    HALF(XA, RB, XB)
    // odd half: consume XB (chunk k+1), convert RA->XA (chunk k+2),
    //           load RB <- chunk k+3
    const f4* psB = (k + 3 < 64) ? (p2 + 8) : xr;  // wrap: dummy reload
    LD8(RB, psB)
    HALF(XB, RA, XA)
    p2 += 16;
  }

  // Epilogue: out[b, c] = sum_j h[j] * W_fc[c, j] + b_fc[c]  (R2-proven)
  float p0 = h * W_fc[j];
  float p1 = h * W_fc[16 + j];
  p0 += __int_as_float(__builtin_amdgcn_ds_swizzle(__float_as_int(p0), 0x041F));
  p1 += __int_as_float(__builtin_amdgcn_ds_swizzle(__float_as_int(p1), 0x041F));
  p0 += __int_as_float(__builtin_amdgcn_ds_swizzle(__float_as_int(p0), 0x081F));
  p1 += __int_as_float(__builtin_amdgcn_ds_swizzle(__float_as_int(p1), 0x081F));
  p0 += __int_as_float(__builtin_amdgcn_ds_swizzle(__float_as_int(p0), 0x101F));
  p1 += __int_as_float(__builtin_amdgcn_ds_swizzle(__float_as_int(p1), 0x101F));
  p0 += __int_as_float(__builtin_amdgcn_ds_swizzle(__float_as_int(p0), 0x201F));
  p1 += __int_as_float(__builtin_amdgcn_ds_swizzle(__float_as_int(p1), 0x201F));

  if (j == 0) {
    out[b * 2 + 0] = p0 + b_fc[0];
    out[b * 2 + 1] = p1 + b_fc[1];
  }
}

// --- launch -----------------------------------------------------------------
extern "C" void kernel_launch(void* const* d_in, const int* in_sizes, int n_in,
                              void* d_out, int out_size, void* d_ws, size_t ws_size,
                              hipStream_t stream) {
  const float* x    = (const float*)d_in[0];
  const float* W_ih = (const float*)d_in[1];
  const float* b_ih = (const float*)d_in[2];
  const float* W_hh = (const float*)d_in[3];
  const float* b_hh = (const float*)d_in[4];
  const float* W_fc = (const float*)d_in[5];
  const float* b_fc = (const float*)d_in[6];
  float* out = (float*)d_out;

  const int B = 4096;
  dim3 grid(B / 16);   // 256 blocks: 4 batches per wave, 1024 waves = 1/SIMD
  dim3 block(256);
  hipLaunchKernelGGL(rnn_relu_kernel, grid, block, 0, stream,
                     x, W_ih, b_ih, W_hh, b_hh, W_fc, b_fc, out);
}

// Round 8
// 93.595 us; speedup vs baseline: 1.1023x; 1.1023x over previous
//
#include <hip/hip_runtime.h>

#define T_LEN 2048

typedef float f4 __attribute__((ext_vector_type(4)));

// --- one timestep ------------------------------------------------------------
// h_new[j] = relu( xi_t[j] + sum_k W_hh[j,k]*h[k] ), xi_t = x_t*wih + bias.
// 20 insts, 3 accumulator chains (spacing 3 insts >= FMA latency), 2-level
// tail. I1 precomputes NEXT step's xi (independent -> fills the h-interlock
// and gives the required 2 instructions between the previous max's h-write
// and the first DPP read of h). All h-reads after I2 are fused DPP.
__device__ __forceinline__ void step(float& h, float& xi, float xsn,
                                     const float (&w)[16], float wih, float bias) {
  float a0, a1, a2, xon;
  asm("v_fma_f32 %[xon], %[xsn], %[wih], %[bs]\n\t"                       // next xi (indep)
      "v_fma_f32 %[a0], %[h], %[w0], %[xi]\n\t"                           // plain h read
      "v_mul_f32_dpp  %[a1], %[h], %[w1]  row_ror:1  row_mask:0xf bank_mask:0xf\n\t"
      "v_mul_f32_dpp  %[a2], %[h], %[w2]  row_ror:2  row_mask:0xf bank_mask:0xf\n\t"
      "v_fmac_f32_dpp %[a0], %[h], %[w3]  row_ror:3  row_mask:0xf bank_mask:0xf\n\t"
      "v_fmac_f32_dpp %[a1], %[h], %[w4]  row_ror:4  row_mask:0xf bank_mask:0xf\n\t"
      "v_fmac_f32_dpp %[a2], %[h], %[w5]  row_ror:5  row_mask:0xf bank_mask:0xf\n\t"
      "v_fmac_f32_dpp %[a0], %[h], %[w6]  row_ror:6  row_mask:0xf bank_mask:0xf\n\t"
      "v_fmac_f32_dpp %[a1], %[h], %[w7]  row_ror:7  row_mask:0xf bank_mask:0xf\n\t"
      "v_fmac_f32_dpp %[a2], %[h], %[w8]  row_ror:8  row_mask:0xf bank_mask:0xf\n\t"
      "v_fmac_f32_dpp %[a0], %[h], %[w9]  row_ror:9  row_mask:0xf bank_mask:0xf\n\t"
      "v_fmac_f32_dpp %[a1], %[h], %[w10] row_ror:10 row_mask:0xf bank_mask:0xf\n\t"
      "v_fmac_f32_dpp %[a2], %[h], %[w11] row_ror:11 row_mask:0xf bank_mask:0xf\n\t"
      "v_fmac_f32_dpp %[a0], %[h], %[w12] row_ror:12 row_mask:0xf bank_mask:0xf\n\t"
      "v_fmac_f32_dpp %[a1], %[h], %[w13] row_ror:13 row_mask:0xf bank_mask:0xf\n\t"
      "v_fmac_f32_dpp %[a2], %[h], %[w14] row_ror:14 row_mask:0xf bank_mask:0xf\n\t"
      "v_fmac_f32_dpp %[a0], %[h], %[w15] row_ror:15 row_mask:0xf bank_mask:0xf\n\t"
      "v_add_f32 %[a1], %[a1], %[a2]\n\t"
      "v_add_f32 %[a0], %[a0], %[a1]\n\t"
      "v_max_f32 %[h], 0, %[a0]"
      : [xon] "=&v"(xon), [a0] "=&v"(a0), [a1] "=&v"(a1), [a2] "=&v"(a2),
        [h] "+v"(h)
      : [xi] "v"(xi), [xsn] "v"(xsn), [wih] "v"(wih), [bs] "v"(bias),
        [w0] "v"(w[0]),  [w1] "v"(w[1]),  [w2] "v"(w[2]),  [w3] "v"(w[3]),
        [w4] "v"(w[4]),  [w5] "v"(w[5]),  [w6] "v"(w[6]),  [w7] "v"(w[7]),
        [w8] "v"(w[8]),  [w9] "v"(w[9]),  [w10] "v"(w[10]), [w11] "v"(w[11]),
        [w12] "v"(w[12]), [w13] "v"(w[13]), [w14] "v"(w[14]), [w15] "v"(w[15]));
  xi = xon;
}

// Each step consumes xi_t (carried) and feeds x_{t+1} to the head-filler.
#define S1(XN) step(h, xi, (XN), w, wih, bias);
#define HALF_A                                                              \
  S1(A0.y) S1(A0.z) S1(A0.w) S1(A1.x) S1(A1.y) S1(A1.z) S1(A1.w) S1(A2.x)  \
  S1(A2.y) S1(A2.z) S1(A2.w) S1(A3.x) S1(A3.y) S1(A3.z) S1(A3.w) S1(B0.x)
#define HALF_B                                                              \
  S1(B0.y) S1(B0.z) S1(B0.w) S1(B1.x) S1(B1.y) S1(B1.z) S1(B1.w) S1(B2.x)  \
  S1(B2.y) S1(B2.z) S1(B2.w) S1(B3.x) S1(B3.y) S1(B3.z) S1(B3.w) S1(A0.x)

// --- kernel ------------------------------------------------------------------
__global__ __launch_bounds__(256) void rnn_relu_kernel(
    const float* __restrict__ x, const float* __restrict__ W_ih,
    const float* __restrict__ b_ih, const float* __restrict__ W_hh,
    const float* __restrict__ b_hh, const float* __restrict__ W_fc,
    const float* __restrict__ b_fc, float* __restrict__ out) {
  const int tid = threadIdx.x;
  const int j   = tid & 15;                        // h index owned by this lane
  const int b   = blockIdx.x * 16 + (tid >> 4);    // batch per 16-lane row

  // Probe row_ror:1 direction (ctrl 0x121 == asm row_ror:1), R1/R2-proven.
  int pr = __builtin_amdgcn_update_dpp(0, j, 0x121, 0xF, 0xF, true);
  const bool plus = (pr == ((j + 1) & 15));

  // w[s] = W_hh[j][sigma_s(j)] so ror_s(h)*w[s] contributes W_hh[j,k]*h[k].
  float w[16];
#pragma unroll
  for (int s = 0; s < 16; ++s) {
    int k = (j + (plus ? s : (16 - s))) & 15;
    w[s] = W_hh[j * 16 + k];
  }
  const float wih  = W_ih[j];
  const float bias = b_ih[j] + b_hh[j];

  // R6-proven load pipeline: A/B double-buffered f4 quads, loads issued a
  // full 16 steps before first use; no copies, no branch in body.
  const f4* __restrict__ xr = (const f4*)(x + (size_t)b * T_LEN);

  float h = 0.0f;
  f4 A0 = xr[0], A1 = xr[1], A2 = xr[2], A3 = xr[3];
  f4 B0, B1, B2, B3;
  float xi = fmaf(A0.x, wih, bias);        // xi for step 0
  const f4* p = xr + 4;                    // chunk t0+16 (B source)

#pragma unroll 1
  for (int t0 = 0; t0 < T_LEN; t0 += 32) {
    B0 = p[0]; B1 = p[1]; B2 = p[2]; B3 = p[3];     // load chunk t0+16
    HALF_A                                           // steps t0 .. t0+15
    const f4* pa = (t0 + 32 < T_LEN) ? (p + 4) : xr; // wrap on final iter
    A0 = pa[0]; A1 = pa[1]; A2 = pa[2]; A3 = pa[3];  // load chunk t0+32
    HALF_B                                           // steps t0+16 .. t0+31
    p += 8;
  }
  // (final step's xi-prefetch reads wrapped x[0] -- value discarded)

  // Epilogue: out[b, c] = sum_j h[j] * W_fc[c, j] + b_fc[c]  (R2-proven)
  float p0 = h * W_fc[j];
  float p1 = h * W_fc[16 + j];
  p0 += __int_as_float(__builtin_amdgcn_ds_swizzle(__float_as_int(p0), 0x041F));
  p1 += __int_as_float(__builtin_amdgcn_ds_swizzle(__float_as_int(p1), 0x041F));
  p0 += __int_as_float(__builtin_amdgcn_ds_swizzle(__float_as_int(p0), 0x081F));
  p1 += __int_as_float(__builtin_amdgcn_ds_swizzle(__float_as_int(p1), 0x081F));
  p0 += __int_as_float(__builtin_amdgcn_ds_swizzle(__float_as_int(p0), 0x101F));
  p1 += __int_as_float(__builtin_amdgcn_ds_swizzle(__float_as_int(p1), 0x101F));
  p0 += __int_as_float(__builtin_amdgcn_ds_swizzle(__float_as_int(p0), 0x201F));
  p1 += __int_as_float(__builtin_amdgcn_ds_swizzle(__float_as_int(p1), 0x201F));

  if (j == 0) {
    out[b * 2 + 0] = p0 + b_fc[0];
    out[b * 2 + 1] = p1 + b_fc[1];
  }
}

// --- launch ------------------------------------------------------------------
extern "C" void kernel_launch(void* const* d_in, const int* in_sizes, int n_in,
                              void* d_out, int out_size, void* d_ws, size_t ws_size,
                              hipStream_t stream) {
  const float* x    = (const float*)d_in[0];
  const float* W_ih = (const float*)d_in[1];
  const float* b_ih = (const float*)d_in[2];
  const float* W_hh = (const float*)d_in[3];
  const float* b_hh = (const float*)d_in[4];
  const float* W_fc = (const float*)d_in[5];
  const float* b_fc = (const float*)d_in[6];
  float* out = (float*)d_out;

  const int B = 4096;
  dim3 grid(B / 16);   // 256 blocks: 4 batches/wave, 1024 waves = 1/SIMD
  dim3 block(256);
  hipLaunchKernelGGL(rnn_relu_kernel, grid, block, 0, stream,
                     x, W_ih, b_ih, W_hh, b_hh, W_fc, b_fc, out);
}